// Round 1
// baseline (1190.455 us; speedup 1.0000x reference)
//
#include <hip/hip_runtime.h>

#define PROP_ALPHA 0.1f

// ------------------------------------------------------------------
// Edge dtype detection: if input is int64 (little-endian, values < 2^31),
// every odd 32-bit word is zero. flag=1 => int32 input.
// ------------------------------------------------------------------
__global__ void detect_kernel(const unsigned int* __restrict__ edges, int* flag) {
    unsigned v = 0;
    for (int i = threadIdx.x * 2 + 1; i < 2048; i += 512) v |= edges[i];
    if (v) atomicOr(flag, 1);
}

__global__ void convert_kernel(const void* __restrict__ edges, const int* __restrict__ flag,
                               int* __restrict__ src, int* __restrict__ dst, int E) {
    int e = blockIdx.x * 256 + threadIdx.x;
    if (e >= E) return;
    if (*flag) {  // int32
        const int* p = (const int*)edges;
        src[e] = p[e];
        dst[e] = p[E + e];
    } else {      // int64
        const long long* p = (const long long*)edges;
        src[e] = (int)p[e];
        dst[e] = (int)p[E + e];
    }
}

__global__ void count_kernel(const int* __restrict__ dst, int* __restrict__ counts, int E) {
    int e = blockIdx.x * 256 + threadIdx.x;
    if (e < E) atomicAdd(&counts[dst[e]], 1);
}

__global__ void dinv_kernel(const int* __restrict__ counts, float* __restrict__ dinv, int n) {
    int i = blockIdx.x * 256 + threadIdx.x;
    if (i < n) dinv[i] = rsqrtf((float)counts[i] + 1.0f);
}

// Single-block exclusive scan of counts -> rowptr[0..n], also copies to cursor.
__global__ __launch_bounds__(1024) void scan_kernel(const int* __restrict__ counts,
                                                    int* __restrict__ rowptr,
                                                    int* __restrict__ cursor, int n) {
    __shared__ int sdata[1024];
    __shared__ int s_base;
    int tid = threadIdx.x;
    if (tid == 0) s_base = 0;
    __syncthreads();
    for (int start = 0; start < n; start += 1024) {
        int i = start + tid;
        int v = (i < n) ? counts[i] : 0;
        sdata[tid] = v;
        __syncthreads();
        #pragma unroll
        for (int off = 1; off < 1024; off <<= 1) {
            int t = (tid >= off) ? sdata[tid - off] : 0;
            __syncthreads();
            sdata[tid] += t;
            __syncthreads();
        }
        int excl = s_base + sdata[tid] - v;  // s_base stable here (barrier below before update)
        if (i < n) { rowptr[i] = excl; cursor[i] = excl; }
        __syncthreads();
        if (tid == 1023) s_base += sdata[1023];
        __syncthreads();
    }
    if (tid == 0) rowptr[n] = s_base;
}

__global__ void fill_kernel(const int* __restrict__ src, const int* __restrict__ dst,
                            const float* __restrict__ dinv, int* __restrict__ cursor,
                            int* __restrict__ csr_src, float* __restrict__ csr_w, int E) {
    int e = blockIdx.x * 256 + threadIdx.x;
    if (e >= E) return;
    int s = src[e], d = dst[e];
    int pos = atomicAdd(&cursor[d], 1);
    csr_src[pos] = s;
    csr_w[pos] = dinv[s] * dinv[d];
}

// ------------------------------------------------------------------
// fp32 tiled GEMM: C[M,N] = act(A[M,K] @ B[N,K]^T + bias[N])
// BM=128, BN=64, BK=32, 256 threads, 8x4 microtile.
// ------------------------------------------------------------------
template<bool RELU>
__global__ __launch_bounds__(256)
void gemm_kernel(const float* __restrict__ A, const float* __restrict__ B,
                 const float* __restrict__ bias, float* __restrict__ C,
                 float* __restrict__ C2, int M, int N, int K) {
    constexpr int BM = 128, BN = 64, BK = 32;
    constexpr int TM = 8, TN = 4;
    constexpr int LDA = BM + 4;  // keep 16B alignment for b128 reads
    constexpr int LDB = BN + 4;
    __shared__ float sa[BK * LDA];  // sa[k][m]
    __shared__ float sb[BK * LDB];  // sb[k][n]

    int tid  = threadIdx.x;
    int trow = tid >> 4;       // 0..15, covers TM=8 rows each
    int tcol = tid & 15;       // 0..15, covers TN=4 cols each
    int gm0 = blockIdx.x * BM;
    int gn0 = blockIdx.y * BN;

    float acc[TM][TN];
    #pragma unroll
    for (int i = 0; i < TM; ++i)
        #pragma unroll
        for (int j = 0; j < TN; ++j) acc[i][j] = 0.0f;

    int lr = tid >> 3;        // 0..31
    int lc = (tid & 7) * 4;   // 0..28 step 4

    for (int k0 = 0; k0 < K; k0 += BK) {
        // stage A tile (BM x BK), transposed into sa[k][m]
        #pragma unroll
        for (int j = 0; j < BM / 32; ++j) {
            int r = lr + 32 * j;
            int gr = gm0 + r;
            if (gr >= M) gr = M - 1;  // safe dummy row; stores guarded
            float4 v = *reinterpret_cast<const float4*>(&A[(size_t)gr * K + k0 + lc]);
            sa[(lc + 0) * LDA + r] = v.x;
            sa[(lc + 1) * LDA + r] = v.y;
            sa[(lc + 2) * LDA + r] = v.z;
            sa[(lc + 3) * LDA + r] = v.w;
        }
        // stage B tile (BN x BK), transposed into sb[k][n]
        #pragma unroll
        for (int j = 0; j < BN / 32; ++j) {
            int r = lr + 32 * j;
            float4 v = *reinterpret_cast<const float4*>(&B[(size_t)(gn0 + r) * K + k0 + lc]);
            sb[(lc + 0) * LDB + r] = v.x;
            sb[(lc + 1) * LDB + r] = v.y;
            sb[(lc + 2) * LDB + r] = v.z;
            sb[(lc + 3) * LDB + r] = v.w;
        }
        __syncthreads();
        #pragma unroll
        for (int k = 0; k < BK; ++k) {
            float4 a0 = *reinterpret_cast<const float4*>(&sa[k * LDA + trow * TM]);
            float4 a1 = *reinterpret_cast<const float4*>(&sa[k * LDA + trow * TM + 4]);
            float4 b0 = *reinterpret_cast<const float4*>(&sb[k * LDB + tcol * TN]);
            float a[TM] = {a0.x, a0.y, a0.z, a0.w, a1.x, a1.y, a1.z, a1.w};
            float b[TN] = {b0.x, b0.y, b0.z, b0.w};
            #pragma unroll
            for (int i = 0; i < TM; ++i)
                #pragma unroll
                for (int j = 0; j < TN; ++j) acc[i][j] += a[i] * b[j];
        }
        __syncthreads();
    }

    float4 bv = *reinterpret_cast<const float4*>(&bias[gn0 + tcol * TN]);
    float bvs[4] = {bv.x, bv.y, bv.z, bv.w};
    #pragma unroll
    for (int i = 0; i < TM; ++i) {
        int gm = gm0 + trow * TM + i;
        if (gm >= M) continue;
        float4 out;
        float* o = &out.x;
        #pragma unroll
        for (int j = 0; j < TN; ++j) {
            float v = acc[i][j] + bvs[j];
            if (RELU) v = fmaxf(v, 0.0f);
            o[j] = v;
        }
        size_t off = (size_t)gm * N + gn0 + tcol * TN;
        *reinterpret_cast<float4*>(&C[off]) = out;
        if (C2) *reinterpret_cast<float4*>(&C2[off]) = out;
    }
}

// ------------------------------------------------------------------
// Propagation step: one wave per node, lane = output channel (64 == wave size).
// hout = (1-a) * (sum_{e in-edges} hin[src_e]*w_e + hin*dinv^2) + a*z
// ------------------------------------------------------------------
__global__ __launch_bounds__(256)
void prop_kernel(const float* __restrict__ hin, const float* __restrict__ z,
                 const int* __restrict__ rowptr, const int* __restrict__ csr_src,
                 const float* __restrict__ csr_w, const float* __restrict__ dinv,
                 float* __restrict__ hout, int n) {
    int node = blockIdx.x * 4 + (threadIdx.x >> 6);
    int lane = threadIdx.x & 63;
    if (node >= n) return;
    float di = dinv[node];
    float acc = hin[(node << 6) + lane] * (di * di);
    int e0 = rowptr[node], e1 = rowptr[node + 1];
    for (int e = e0; e < e1; ++e) {
        int s = csr_src[e];
        float w = csr_w[e];
        acc += hin[(s << 6) + lane] * w;
    }
    hout[(node << 6) + lane] = (1.0f - PROP_ALPHA) * acc + PROP_ALPHA * z[(node << 6) + lane];
}

// ------------------------------------------------------------------
extern "C" void kernel_launch(void* const* d_in, const int* in_sizes, int n_in,
                              void* d_out, int out_size, void* d_ws, size_t ws_size,
                              hipStream_t stream) {
    const float* x  = (const float*)d_in[0];
    const void*  ei = d_in[1];
    const float* W1 = (const float*)d_in[2];
    const float* b1 = (const float*)d_in[3];
    const float* W2 = (const float*)d_in[4];
    const float* b2 = (const float*)d_in[5];
    float* dout = (float*)d_out;

    const int IN_C = 512, HID_C = 256, OUT_C = 64, Ksteps = 10;
    const int N = in_sizes[0] / IN_C;   // 50000
    const int E = in_sizes[1] / 2;      // 800000

    // workspace carve (256B aligned)
    char* w = (char*)d_ws;
    auto alloc = [&](size_t bytes) { char* p = w; w += (bytes + 255) & ~(size_t)255; return p; };
    int*   flag    = (int*)  alloc(4);
    int*   src32   = (int*)  alloc((size_t)E * 4);
    int*   dst32   = (int*)  alloc((size_t)E * 4);
    int*   counts  = (int*)  alloc((size_t)N * 4);
    int*   rowptr  = (int*)  alloc((size_t)(N + 1) * 4);
    int*   cursor  = (int*)  alloc((size_t)N * 4);
    float* dinv    = (float*)alloc((size_t)N * 4);
    int*   csr_src = (int*)  alloc((size_t)E * 4);
    float* csr_w   = (float*)alloc((size_t)E * 4);
    float* h       = (float*)alloc((size_t)N * HID_C * 4);
    float* zbuf    = (float*)alloc((size_t)N * OUT_C * 4);
    float* hB      = (float*)alloc((size_t)N * OUT_C * 4);

    hipMemsetAsync(flag, 0, 4, stream);
    hipMemsetAsync(counts, 0, (size_t)N * 4, stream);

    int egrid = (E + 255) / 256;
    int ngrid = (N + 255) / 256;

    detect_kernel<<<1, 256, 0, stream>>>((const unsigned int*)ei, flag);
    convert_kernel<<<egrid, 256, 0, stream>>>(ei, flag, src32, dst32, E);
    count_kernel<<<egrid, 256, 0, stream>>>(dst32, counts, E);
    dinv_kernel<<<ngrid, 256, 0, stream>>>(counts, dinv, N);
    scan_kernel<<<1, 1024, 0, stream>>>(counts, rowptr, cursor, N);
    fill_kernel<<<egrid, 256, 0, stream>>>(src32, dst32, dinv, cursor, csr_src, csr_w, E);

    // MLP: h = relu(x @ W1^T + b1); z = h @ W2^T + b2  (z -> zbuf and d_out = h^(0))
    dim3 g1((N + 127) / 128, HID_C / 64);
    gemm_kernel<true><<<g1, 256, 0, stream>>>(x, W1, b1, h, nullptr, N, HID_C, IN_C);
    dim3 g2((N + 127) / 128, OUT_C / 64);
    gemm_kernel<false><<<g2, 256, 0, stream>>>(h, W2, b2, zbuf, dout, N, OUT_C, HID_C);

    // K propagation steps, ping-pong dout <-> hB; 10 steps end in dout.
    int pgrid = (N + 3) / 4;
    for (int s = 0; s < Ksteps; ++s) {
        const float* in  = (s % 2 == 0) ? dout : hB;
        float*       out = (s % 2 == 0) ? hB   : dout;
        prop_kernel<<<pgrid, 256, 0, stream>>>(in, zbuf, rowptr, csr_src, csr_w, dinv, out, N);
    }
}

// Round 2
// 661.627 us; speedup vs baseline: 1.7993x; 1.7993x over previous
//
#include <hip/hip_runtime.h>

// ------------------------------------------------------------------
// Edge dtype detection: if input is int64 (little-endian, values < 2^31),
// every odd 32-bit word is zero. flag=1 => int32 input.
// ------------------------------------------------------------------
__global__ void detect_kernel(const unsigned int* __restrict__ edges, int* flag) {
    unsigned v = 0;
    for (int i = threadIdx.x * 2 + 1; i < 2048; i += 512) v |= edges[i];
    if (v) atomicOr(flag, 1);
}

// convert edges to int32 src/dst AND count in-degree in one pass
__global__ void convert_count_kernel(const void* __restrict__ edges, const int* __restrict__ flag,
                                     int* __restrict__ src, int* __restrict__ dst,
                                     int* __restrict__ counts, int E) {
    int e = blockIdx.x * 256 + threadIdx.x;
    if (e >= E) return;
    int s, d;
    if (*flag) {  // int32
        const int* p = (const int*)edges;
        s = p[e];
        d = p[E + e];
    } else {      // int64
        const long long* p = (const long long*)edges;
        s = (int)p[e];
        d = (int)p[E + e];
    }
    src[e] = s;
    dst[e] = d;
    atomicAdd(&counts[d], 1);
}

__global__ void dinv_kernel(const int* __restrict__ counts, float* __restrict__ dinv, int n) {
    int i = blockIdx.x * 256 + threadIdx.x;
    if (i < n) dinv[i] = rsqrtf((float)counts[i] + 1.0f);
}

// ---------------- hierarchical exclusive scan (3 kernels) ----------------
__global__ void blocksum_kernel(const int* __restrict__ counts, int* __restrict__ bs, int n) {
    __shared__ int sdata[256];
    int i = blockIdx.x * 256 + threadIdx.x;
    sdata[threadIdx.x] = (i < n) ? counts[i] : 0;
    __syncthreads();
    #pragma unroll
    for (int off = 128; off > 0; off >>= 1) {
        if (threadIdx.x < off) sdata[threadIdx.x] += sdata[threadIdx.x + off];
        __syncthreads();
    }
    if (threadIdx.x == 0) bs[blockIdx.x] = sdata[0];
}

__global__ void scanbs_kernel(const int* __restrict__ bs, int* __restrict__ bsoff, int nb) {
    // nb <= 256; single block exclusive scan
    __shared__ int sdata[256];
    int tid = threadIdx.x;
    int v = (tid < nb) ? bs[tid] : 0;
    sdata[tid] = v;
    __syncthreads();
    #pragma unroll
    for (int off = 1; off < 256; off <<= 1) {
        int t = (tid >= off) ? sdata[tid - off] : 0;
        __syncthreads();
        sdata[tid] += t;
        __syncthreads();
    }
    if (tid < nb) bsoff[tid] = sdata[tid] - v;
}

__global__ void scanblock_kernel(const int* __restrict__ counts, const int* __restrict__ bsoff,
                                 int* __restrict__ rowptr, int* __restrict__ cursor, int n) {
    __shared__ int sdata[256];
    int tid = threadIdx.x;
    int i = blockIdx.x * 256 + tid;
    int v = (i < n) ? counts[i] : 0;
    sdata[tid] = v;
    __syncthreads();
    #pragma unroll
    for (int off = 1; off < 256; off <<= 1) {
        int t = (tid >= off) ? sdata[tid - off] : 0;
        __syncthreads();
        sdata[tid] += t;
        __syncthreads();
    }
    int excl = bsoff[blockIdx.x] + sdata[tid] - v;
    if (i < n) { rowptr[i] = excl; cursor[i] = excl; }
    if (i == n - 1) rowptr[n] = excl + v;
}

__global__ void fill_kernel(const int* __restrict__ src, const int* __restrict__ dst,
                            const float* __restrict__ dinv, int* __restrict__ cursor,
                            int* __restrict__ csr_src, float* __restrict__ csr_w, int E) {
    int e = blockIdx.x * 256 + threadIdx.x;
    if (e >= E) return;
    int s = src[e], d = dst[e];
    int pos = atomicAdd(&cursor[d], 1);
    csr_src[pos] = s;
    csr_w[pos] = dinv[s] * dinv[d];
}

// ------------------------------------------------------------------
// fp32 tiled GEMM: C[M,N] = act(A[M,K] @ B[N,K]^T + bias[N])
// BM=128, BN=64, BK=32, 256 threads, 8x4 microtile.
// ------------------------------------------------------------------
template<bool RELU>
__global__ __launch_bounds__(256)
void gemm_kernel(const float* __restrict__ A, const float* __restrict__ B,
                 const float* __restrict__ bias, float* __restrict__ C,
                 float* __restrict__ C2, int M, int N, int K) {
    constexpr int BM = 128, BN = 64, BK = 32;
    constexpr int TM = 8, TN = 4;
    constexpr int LDA = BM + 4;
    constexpr int LDB = BN + 4;
    __shared__ float sa[BK * LDA];  // sa[k][m]
    __shared__ float sb[BK * LDB];  // sb[k][n]

    int tid  = threadIdx.x;
    int trow = tid >> 4;
    int tcol = tid & 15;
    int gm0 = blockIdx.x * BM;
    int gn0 = blockIdx.y * BN;

    float acc[TM][TN];
    #pragma unroll
    for (int i = 0; i < TM; ++i)
        #pragma unroll
        for (int j = 0; j < TN; ++j) acc[i][j] = 0.0f;

    int lr = tid >> 3;
    int lc = (tid & 7) * 4;

    for (int k0 = 0; k0 < K; k0 += BK) {
        #pragma unroll
        for (int j = 0; j < BM / 32; ++j) {
            int r = lr + 32 * j;
            int gr = gm0 + r;
            if (gr >= M) gr = M - 1;
            float4 v = *reinterpret_cast<const float4*>(&A[(size_t)gr * K + k0 + lc]);
            sa[(lc + 0) * LDA + r] = v.x;
            sa[(lc + 1) * LDA + r] = v.y;
            sa[(lc + 2) * LDA + r] = v.z;
            sa[(lc + 3) * LDA + r] = v.w;
        }
        #pragma unroll
        for (int j = 0; j < BN / 32; ++j) {
            int r = lr + 32 * j;
            float4 v = *reinterpret_cast<const float4*>(&B[(size_t)(gn0 + r) * K + k0 + lc]);
            sb[(lc + 0) * LDB + r] = v.x;
            sb[(lc + 1) * LDB + r] = v.y;
            sb[(lc + 2) * LDB + r] = v.z;
            sb[(lc + 3) * LDB + r] = v.w;
        }
        __syncthreads();
        #pragma unroll
        for (int k = 0; k < BK; ++k) {
            float4 a0 = *reinterpret_cast<const float4*>(&sa[k * LDA + trow * TM]);
            float4 a1 = *reinterpret_cast<const float4*>(&sa[k * LDA + trow * TM + 4]);
            float4 b0 = *reinterpret_cast<const float4*>(&sb[k * LDB + tcol * TN]);
            float a[TM] = {a0.x, a0.y, a0.z, a0.w, a1.x, a1.y, a1.z, a1.w};
            float b[TN] = {b0.x, b0.y, b0.z, b0.w};
            #pragma unroll
            for (int i = 0; i < TM; ++i)
                #pragma unroll
                for (int j = 0; j < TN; ++j) acc[i][j] += a[i] * b[j];
        }
        __syncthreads();
    }

    float4 bv = *reinterpret_cast<const float4*>(&bias[gn0 + tcol * TN]);
    float bvs[4] = {bv.x, bv.y, bv.z, bv.w};
    #pragma unroll
    for (int i = 0; i < TM; ++i) {
        int gm = gm0 + trow * TM + i;
        if (gm >= M) continue;
        float4 out;
        float* o = &out.x;
        #pragma unroll
        for (int j = 0; j < TN; ++j) {
            float v = acc[i][j] + bvs[j];
            if (RELU) v = fmaxf(v, 0.0f);
            o[j] = v;
        }
        size_t off = (size_t)gm * N + gn0 + tcol * TN;
        *reinterpret_cast<float4*>(&C[off]) = out;
        if (C2) *reinterpret_cast<float4*>(&C2[off]) = out;
    }
}

// ------------------------------------------------------------------
// Propagation step: one wave per node, lane = channel (64 == wave size).
// 8-edge batched gather: load 8 indices/weights (uniform broadcast),
// then issue 8 independent row gathers -> 8x memory-level parallelism.
// ------------------------------------------------------------------
__global__ __launch_bounds__(256)
void prop_kernel(const float* __restrict__ hin, const float* __restrict__ z,
                 const int* __restrict__ rowptr, const int* __restrict__ csr_src,
                 const float* __restrict__ csr_w, const float* __restrict__ dinv,
                 float* __restrict__ hout, int n) {
    int node = blockIdx.x * 4 + (threadIdx.x >> 6);
    int lane = threadIdx.x & 63;
    if (node >= n) return;
    float di = dinv[node];
    int base = node << 6;
    float acc = hin[base + lane] * (di * di);
    int e  = rowptr[node];
    int e1 = rowptr[node + 1];

    for (; e + 8 <= e1; e += 8) {
        int s[8]; float ww[8], v[8];
        #pragma unroll
        for (int j = 0; j < 8; ++j) { s[j] = csr_src[e + j]; ww[j] = csr_w[e + j]; }
        #pragma unroll
        for (int j = 0; j < 8; ++j) v[j] = hin[(s[j] << 6) + lane];
        #pragma unroll
        for (int j = 0; j < 8; ++j) acc = fmaf(v[j], ww[j], acc);
    }
    for (; e + 2 <= e1; e += 2) {
        int s0 = csr_src[e], s1 = csr_src[e + 1];
        float w0 = csr_w[e], w1 = csr_w[e + 1];
        float v0 = hin[(s0 << 6) + lane];
        float v1 = hin[(s1 << 6) + lane];
        acc = fmaf(v0, w0, acc);
        acc = fmaf(v1, w1, acc);
    }
    if (e < e1) {
        acc = fmaf(hin[(csr_src[e] << 6) + lane], csr_w[e], acc);
    }
    hout[base + lane] = 0.9f * acc + 0.1f * z[base + lane];
}

// ------------------------------------------------------------------
extern "C" void kernel_launch(void* const* d_in, const int* in_sizes, int n_in,
                              void* d_out, int out_size, void* d_ws, size_t ws_size,
                              hipStream_t stream) {
    const float* x  = (const float*)d_in[0];
    const void*  ei = d_in[1];
    const float* W1 = (const float*)d_in[2];
    const float* b1 = (const float*)d_in[3];
    const float* W2 = (const float*)d_in[4];
    const float* b2 = (const float*)d_in[5];
    float* dout = (float*)d_out;

    const int IN_C = 512, HID_C = 256, OUT_C = 64, Ksteps = 10;
    const int N = in_sizes[0] / IN_C;   // 50000
    const int E = in_sizes[1] / 2;      // 800000

    char* w = (char*)d_ws;
    auto alloc = [&](size_t bytes) { char* p = w; w += (bytes + 255) & ~(size_t)255; return p; };
    int*   flag    = (int*)  alloc(4);
    int*   src32   = (int*)  alloc((size_t)E * 4);
    int*   dst32   = (int*)  alloc((size_t)E * 4);
    int*   counts  = (int*)  alloc((size_t)N * 4);
    int*   rowptr  = (int*)  alloc((size_t)(N + 1) * 4);
    int*   cursor  = (int*)  alloc((size_t)N * 4);
    float* dinv    = (float*)alloc((size_t)N * 4);
    int*   csr_src = (int*)  alloc((size_t)E * 4);
    float* csr_w   = (float*)alloc((size_t)E * 4);
    float* h       = (float*)alloc((size_t)N * HID_C * 4);
    float* zbuf    = (float*)alloc((size_t)N * OUT_C * 4);
    float* hB      = (float*)alloc((size_t)N * OUT_C * 4);
    int nblk = (N + 255) / 256;
    int*   bs      = (int*)  alloc((size_t)nblk * 4);
    int*   bsoff   = (int*)  alloc((size_t)nblk * 4);

    hipMemsetAsync(flag, 0, 4, stream);
    hipMemsetAsync(counts, 0, (size_t)N * 4, stream);

    int egrid = (E + 255) / 256;

    detect_kernel<<<1, 256, 0, stream>>>((const unsigned int*)ei, flag);
    convert_count_kernel<<<egrid, 256, 0, stream>>>(ei, flag, src32, dst32, counts, E);
    dinv_kernel<<<nblk, 256, 0, stream>>>(counts, dinv, N);
    blocksum_kernel<<<nblk, 256, 0, stream>>>(counts, bs, N);
    scanbs_kernel<<<1, 256, 0, stream>>>(bs, bsoff, nblk);
    scanblock_kernel<<<nblk, 256, 0, stream>>>(counts, bsoff, rowptr, cursor, N);
    fill_kernel<<<egrid, 256, 0, stream>>>(src32, dst32, dinv, cursor, csr_src, csr_w, E);

    // MLP: h = relu(x @ W1^T + b1); z = h @ W2^T + b2  (z -> zbuf and d_out = h^(0))
    dim3 g1((N + 127) / 128, HID_C / 64);
    gemm_kernel<true><<<g1, 256, 0, stream>>>(x, W1, b1, h, nullptr, N, HID_C, IN_C);
    dim3 g2((N + 127) / 128, OUT_C / 64);
    gemm_kernel<false><<<g2, 256, 0, stream>>>(h, W2, b2, zbuf, dout, N, OUT_C, HID_C);

    // K propagation steps, ping-pong dout <-> hB; 10 steps end in dout.
    int pgrid = (N + 3) / 4;
    for (int s = 0; s < Ksteps; ++s) {
        const float* in  = (s % 2 == 0) ? dout : hB;
        float*       out = (s % 2 == 0) ? hB   : dout;
        prop_kernel<<<pgrid, 256, 0, stream>>>(in, zbuf, rowptr, csr_src, csr_w, dinv, out, N);
    }
}

// Round 3
// 600.393 us; speedup vs baseline: 1.9828x; 1.1020x over previous
//
#include <hip/hip_runtime.h>

typedef __bf16 bf16x8 __attribute__((ext_vector_type(8)));
typedef float f32x4 __attribute__((ext_vector_type(4)));
typedef short short8 __attribute__((ext_vector_type(8)));

__device__ __forceinline__ unsigned short f2bf_u(float f) {
    unsigned u = __builtin_bit_cast(unsigned, f);
    u += 0x7FFFu + ((u >> 16) & 1u);   // RNE
    return (unsigned short)(u >> 16);
}
__device__ __forceinline__ float bf2f(unsigned short h) {
    unsigned u = ((unsigned)h) << 16;
    return __builtin_bit_cast(float, u);
}

// ------------------------------------------------------------------
// Edge dtype detection: int64 input => odd 32-bit words all zero.
// ------------------------------------------------------------------
__global__ void detect_kernel(const unsigned int* __restrict__ edges, int* flag) {
    unsigned v = 0;
    for (int i = threadIdx.x * 2 + 1; i < 2048; i += 512) v |= edges[i];
    if (v) atomicOr(flag, 1);
}

__global__ void convert_count_kernel(const void* __restrict__ edges, const int* __restrict__ flag,
                                     int* __restrict__ src, int* __restrict__ dst,
                                     int* __restrict__ counts, int E) {
    int e = blockIdx.x * 256 + threadIdx.x;
    if (e >= E) return;
    int s, d;
    if (*flag) {  // int32
        const int* p = (const int*)edges;
        s = p[e];
        d = p[E + e];
    } else {      // int64
        const long long* p = (const long long*)edges;
        s = (int)p[e];
        d = (int)p[E + e];
    }
    src[e] = s;
    dst[e] = d;
    atomicAdd(&counts[d], 1);
}

__global__ void dinv_kernel(const int* __restrict__ counts, float* __restrict__ dinv, int n) {
    int i = blockIdx.x * 256 + threadIdx.x;
    if (i < n) dinv[i] = rsqrtf((float)counts[i] + 1.0f);
}

// ---------------- hierarchical exclusive scan ----------------
__global__ void blocksum_kernel(const int* __restrict__ counts, int* __restrict__ bs, int n) {
    __shared__ int sdata[256];
    int i = blockIdx.x * 256 + threadIdx.x;
    sdata[threadIdx.x] = (i < n) ? counts[i] : 0;
    __syncthreads();
    #pragma unroll
    for (int off = 128; off > 0; off >>= 1) {
        if (threadIdx.x < off) sdata[threadIdx.x] += sdata[threadIdx.x + off];
        __syncthreads();
    }
    if (threadIdx.x == 0) bs[blockIdx.x] = sdata[0];
}

__global__ void scanbs_kernel(const int* __restrict__ bs, int* __restrict__ bsoff, int nb) {
    __shared__ int sdata[256];
    int tid = threadIdx.x;
    int v = (tid < nb) ? bs[tid] : 0;
    sdata[tid] = v;
    __syncthreads();
    #pragma unroll
    for (int off = 1; off < 256; off <<= 1) {
        int t = (tid >= off) ? sdata[tid - off] : 0;
        __syncthreads();
        sdata[tid] += t;
        __syncthreads();
    }
    if (tid < nb) bsoff[tid] = sdata[tid] - v;
}

__global__ void scanblock_kernel(const int* __restrict__ counts, const int* __restrict__ bsoff,
                                 int* __restrict__ rowptr, int* __restrict__ cursor, int n) {
    __shared__ int sdata[256];
    int tid = threadIdx.x;
    int i = blockIdx.x * 256 + tid;
    int v = (i < n) ? counts[i] : 0;
    sdata[tid] = v;
    __syncthreads();
    #pragma unroll
    for (int off = 1; off < 256; off <<= 1) {
        int t = (tid >= off) ? sdata[tid - off] : 0;
        __syncthreads();
        sdata[tid] += t;
        __syncthreads();
    }
    int excl = bsoff[blockIdx.x] + sdata[tid] - v;
    if (i < n) { rowptr[i] = excl; cursor[i] = excl; }
    if (i == n - 1) rowptr[n] = excl + v;
}

__global__ void fill_kernel(const int* __restrict__ src, const int* __restrict__ dst,
                            const float* __restrict__ dinv, int* __restrict__ cursor,
                            int* __restrict__ csr_src, float* __restrict__ csr_w, int E) {
    int e = blockIdx.x * 256 + threadIdx.x;
    if (e >= E) return;
    int s = src[e], d = dst[e];
    int pos = atomicAdd(&cursor[d], 1);
    csr_src[pos] = s;
    csr_w[pos] = dinv[s] * dinv[d];
}

// ------------------------------------------------------------------
// Weight split: W -> Wh (bf16 RNE) + Wl (bf16 of residual)
// ------------------------------------------------------------------
__global__ void wsplit_kernel(const float* __restrict__ W, short* __restrict__ Wh,
                              short* __restrict__ Wl, int n) {
    int i = blockIdx.x * 256 + threadIdx.x;
    if (i >= n) return;
    float w = W[i];
    unsigned short h = f2bf_u(w);
    Wh[i] = (short)h;
    Wl[i] = (short)f2bf_u(w - bf2f(h));
}

// ------------------------------------------------------------------
// GEMM1: H[M,256] = relu(bf16(x)[M,512] @ (W1h+W1l)^T + b1), H in bf16.
// LDS-free MFMA. Block = 4 waves, wave tile 64x64; block covers 64 rows x N=256.
// ------------------------------------------------------------------
__global__ __launch_bounds__(256)
void gemm1_kernel(const float* __restrict__ A, const short* __restrict__ Bh,
                  const short* __restrict__ Bl, const float* __restrict__ bias,
                  short* __restrict__ H, int M) {
    const int K = 512, N = 256;
    int lane = threadIdx.x & 63;
    int wave = threadIdx.x >> 6;
    int m0 = blockIdx.x * 64;
    int n0 = wave * 64;
    int rlo = lane & 15;
    int kgrp = (lane >> 4) * 8;

    f32x4 acc[4][4];
    #pragma unroll
    for (int i = 0; i < 4; ++i)
        #pragma unroll
        for (int j = 0; j < 4; ++j) acc[i][j] = {0.f, 0.f, 0.f, 0.f};

    const float* pa[4];
    #pragma unroll
    for (int mi = 0; mi < 4; ++mi) {
        int r = m0 + mi * 16 + rlo;
        if (r > M - 1) r = M - 1;            // tail clamp (stores guarded)
        pa[mi] = A + (size_t)r * K + kgrp;
    }
    const short* pbh[4];
    const short* pbl[4];
    #pragma unroll
    for (int ni = 0; ni < 4; ++ni) {
        int nn = n0 + ni * 16 + rlo;
        pbh[ni] = Bh + nn * K + kgrp;
        pbl[ni] = Bl + nn * K + kgrp;
    }

    #pragma unroll 2
    for (int k0 = 0; k0 < K; k0 += 32) {
        bf16x8 af[4], fbh[4], fbl[4];
        #pragma unroll
        for (int mi = 0; mi < 4; ++mi) {
            float4 x0 = *reinterpret_cast<const float4*>(pa[mi]);
            float4 x1 = *reinterpret_cast<const float4*>(pa[mi] + 4);
            short8 s;
            s[0] = (short)f2bf_u(x0.x); s[1] = (short)f2bf_u(x0.y);
            s[2] = (short)f2bf_u(x0.z); s[3] = (short)f2bf_u(x0.w);
            s[4] = (short)f2bf_u(x1.x); s[5] = (short)f2bf_u(x1.y);
            s[6] = (short)f2bf_u(x1.z); s[7] = (short)f2bf_u(x1.w);
            af[mi] = __builtin_bit_cast(bf16x8, s);
            pa[mi] += 32;
        }
        #pragma unroll
        for (int ni = 0; ni < 4; ++ni) {
            fbh[ni] = *reinterpret_cast<const bf16x8*>(pbh[ni]);
            fbl[ni] = *reinterpret_cast<const bf16x8*>(pbl[ni]);
            pbh[ni] += 32;
            pbl[ni] += 32;
        }
        #pragma unroll
        for (int mi = 0; mi < 4; ++mi)
            #pragma unroll
            for (int ni = 0; ni < 4; ++ni) {
                acc[mi][ni] = __builtin_amdgcn_mfma_f32_16x16x32_bf16(af[mi], fbh[ni], acc[mi][ni], 0, 0, 0);
                acc[mi][ni] = __builtin_amdgcn_mfma_f32_16x16x32_bf16(af[mi], fbl[ni], acc[mi][ni], 0, 0, 0);
            }
    }

    int crow0 = (lane >> 4) * 4;
    #pragma unroll
    for (int ni = 0; ni < 4; ++ni) {
        int col = n0 + ni * 16 + rlo;
        float bv = bias[col];
        #pragma unroll
        for (int mi = 0; mi < 4; ++mi) {
            #pragma unroll
            for (int r = 0; r < 4; ++r) {
                int row = m0 + mi * 16 + crow0 + r;
                if (row < M) {
                    float v = fmaxf(acc[mi][ni][r] + bv, 0.0f);
                    H[(size_t)row * N + col] = (short)f2bf_u(v);
                }
            }
        }
    }
}

// ------------------------------------------------------------------
// GEMM2: Z[M,64] = H[M,256]bf16 @ (W2h+W2l)^T + b2 (fp32 out).
// Block = 4 waves, each wave 32 rows x N=64.
// ------------------------------------------------------------------
__global__ __launch_bounds__(256)
void gemm2_kernel(const short* __restrict__ A, const short* __restrict__ Bh,
                  const short* __restrict__ Bl, const float* __restrict__ bias,
                  float* __restrict__ Z, int M) {
    const int K = 256, N = 64;
    int lane = threadIdx.x & 63;
    int wave = threadIdx.x >> 6;
    int m0 = blockIdx.x * 128 + wave * 32;
    int rlo = lane & 15;
    int kgrp = (lane >> 4) * 8;

    f32x4 acc[2][4];
    #pragma unroll
    for (int i = 0; i < 2; ++i)
        #pragma unroll
        for (int j = 0; j < 4; ++j) acc[i][j] = {0.f, 0.f, 0.f, 0.f};

    const short* pa[2];
    #pragma unroll
    for (int mi = 0; mi < 2; ++mi) {
        int r = m0 + mi * 16 + rlo;
        if (r > M - 1) r = M - 1;
        pa[mi] = A + (size_t)r * K + kgrp;
    }
    const short* pbh[4];
    const short* pbl[4];
    #pragma unroll
    for (int ni = 0; ni < 4; ++ni) {
        int nn = ni * 16 + rlo;
        pbh[ni] = Bh + nn * K + kgrp;
        pbl[ni] = Bl + nn * K + kgrp;
    }

    #pragma unroll 2
    for (int k0 = 0; k0 < K; k0 += 32) {
        bf16x8 af[2], fbh[4], fbl[4];
        #pragma unroll
        for (int mi = 0; mi < 2; ++mi) {
            af[mi] = *reinterpret_cast<const bf16x8*>(pa[mi]);
            pa[mi] += 32;
        }
        #pragma unroll
        for (int ni = 0; ni < 4; ++ni) {
            fbh[ni] = *reinterpret_cast<const bf16x8*>(pbh[ni]);
            fbl[ni] = *reinterpret_cast<const bf16x8*>(pbl[ni]);
            pbh[ni] += 32;
            pbl[ni] += 32;
        }
        #pragma unroll
        for (int mi = 0; mi < 2; ++mi)
            #pragma unroll
            for (int ni = 0; ni < 4; ++ni) {
                acc[mi][ni] = __builtin_amdgcn_mfma_f32_16x16x32_bf16(af[mi], fbh[ni], acc[mi][ni], 0, 0, 0);
                acc[mi][ni] = __builtin_amdgcn_mfma_f32_16x16x32_bf16(af[mi], fbl[ni], acc[mi][ni], 0, 0, 0);
            }
    }

    int crow0 = (lane >> 4) * 4;
    #pragma unroll
    for (int ni = 0; ni < 4; ++ni) {
        int col = ni * 16 + rlo;
        float bv = bias[col];
        #pragma unroll
        for (int mi = 0; mi < 2; ++mi) {
            #pragma unroll
            for (int r = 0; r < 4; ++r) {
                int row = m0 + mi * 16 + crow0 + r;
                if (row < M) Z[(size_t)row * N + col] = acc[mi][ni][r] + bv;
            }
        }
    }
}

// ------------------------------------------------------------------
// Propagation step: one wave per node, lane = channel; 8-edge batched gather.
// ------------------------------------------------------------------
__global__ __launch_bounds__(256)
void prop_kernel(const float* __restrict__ hin, const float* __restrict__ z,
                 const int* __restrict__ rowptr, const int* __restrict__ csr_src,
                 const float* __restrict__ csr_w, const float* __restrict__ dinv,
                 float* __restrict__ hout, int n) {
    int node = blockIdx.x * 4 + (threadIdx.x >> 6);
    int lane = threadIdx.x & 63;
    if (node >= n) return;
    float di = dinv[node];
    int base = node << 6;
    float acc = hin[base + lane] * (di * di);
    int e  = rowptr[node];
    int e1 = rowptr[node + 1];

    for (; e + 8 <= e1; e += 8) {
        int s[8]; float ww[8], v[8];
        #pragma unroll
        for (int j = 0; j < 8; ++j) { s[j] = csr_src[e + j]; ww[j] = csr_w[e + j]; }
        #pragma unroll
        for (int j = 0; j < 8; ++j) v[j] = hin[(s[j] << 6) + lane];
        #pragma unroll
        for (int j = 0; j < 8; ++j) acc = fmaf(v[j], ww[j], acc);
    }
    for (; e + 2 <= e1; e += 2) {
        int s0 = csr_src[e], s1 = csr_src[e + 1];
        float w0 = csr_w[e], w1 = csr_w[e + 1];
        float v0 = hin[(s0 << 6) + lane];
        float v1 = hin[(s1 << 6) + lane];
        acc = fmaf(v0, w0, acc);
        acc = fmaf(v1, w1, acc);
    }
    if (e < e1) {
        acc = fmaf(hin[(csr_src[e] << 6) + lane], csr_w[e], acc);
    }
    hout[base + lane] = 0.9f * acc + 0.1f * z[base + lane];
}

// ------------------------------------------------------------------
extern "C" void kernel_launch(void* const* d_in, const int* in_sizes, int n_in,
                              void* d_out, int out_size, void* d_ws, size_t ws_size,
                              hipStream_t stream) {
    const float* x  = (const float*)d_in[0];
    const void*  ei = d_in[1];
    const float* W1 = (const float*)d_in[2];
    const float* b1 = (const float*)d_in[3];
    const float* W2 = (const float*)d_in[4];
    const float* b2 = (const float*)d_in[5];
    float* dout = (float*)d_out;

    const int IN_C = 512, HID_C = 256, OUT_C = 64, Ksteps = 10;
    const int N = in_sizes[0] / IN_C;   // 50000
    const int E = in_sizes[1] / 2;      // 800000

    char* w = (char*)d_ws;
    auto alloc = [&](size_t bytes) { char* p = w; w += (bytes + 255) & ~(size_t)255; return p; };
    int*   flag    = (int*)  alloc(4);
    int*   src32   = (int*)  alloc((size_t)E * 4);
    int*   dst32   = (int*)  alloc((size_t)E * 4);
    int*   counts  = (int*)  alloc((size_t)N * 4);
    int*   rowptr  = (int*)  alloc((size_t)(N + 1) * 4);
    int*   cursor  = (int*)  alloc((size_t)N * 4);
    float* dinv    = (float*)alloc((size_t)N * 4);
    int*   csr_src = (int*)  alloc((size_t)E * 4);
    float* csr_w   = (float*)alloc((size_t)E * 4);
    short* W1h     = (short*)alloc((size_t)HID_C * IN_C * 2);
    short* W1l     = (short*)alloc((size_t)HID_C * IN_C * 2);
    short* W2h     = (short*)alloc((size_t)OUT_C * HID_C * 2);
    short* W2l     = (short*)alloc((size_t)OUT_C * HID_C * 2);
    short* Hbf     = (short*)alloc((size_t)N * HID_C * 2);
    float* zbuf    = (float*)alloc((size_t)N * OUT_C * 4);
    float* hB      = (float*)alloc((size_t)N * OUT_C * 4);
    int nblk = (N + 255) / 256;
    int*   bs      = (int*)  alloc((size_t)nblk * 4);
    int*   bsoff   = (int*)  alloc((size_t)nblk * 4);

    hipMemsetAsync(flag, 0, 4, stream);
    hipMemsetAsync(counts, 0, (size_t)N * 4, stream);

    int egrid = (E + 255) / 256;

    // weight splits (tiny)
    wsplit_kernel<<<(HID_C * IN_C + 255) / 256, 256, 0, stream>>>(W1, W1h, W1l, HID_C * IN_C);
    wsplit_kernel<<<(OUT_C * HID_C + 255) / 256, 256, 0, stream>>>(W2, W2h, W2l, OUT_C * HID_C);

    // graph preprocessing
    detect_kernel<<<1, 256, 0, stream>>>((const unsigned int*)ei, flag);
    convert_count_kernel<<<egrid, 256, 0, stream>>>(ei, flag, src32, dst32, counts, E);
    dinv_kernel<<<nblk, 256, 0, stream>>>(counts, dinv, N);
    blocksum_kernel<<<nblk, 256, 0, stream>>>(counts, bs, N);
    scanbs_kernel<<<1, 256, 0, stream>>>(bs, bsoff, nblk);
    scanblock_kernel<<<nblk, 256, 0, stream>>>(counts, bsoff, rowptr, cursor, N);
    fill_kernel<<<egrid, 256, 0, stream>>>(src32, dst32, dinv, cursor, csr_src, csr_w, E);

    // MLP on matrix cores
    gemm1_kernel<<<(N + 63) / 64, 256, 0, stream>>>(x, W1h, W1l, b1, Hbf, N);
    gemm2_kernel<<<(N + 127) / 128, 256, 0, stream>>>(Hbf, W2h, W2l, b2, zbuf, N);

    // K propagation steps. h^(0) = z lives in zbuf; steps ping-pong hB/dout,
    // ending in dout at s=9 (odd steps write dout).
    int pgrid = (N + 3) / 4;
    for (int s = 0; s < Ksteps; ++s) {
        const float* in  = (s == 0) ? zbuf : ((s & 1) ? hB : dout);
        float*       out = (s & 1) ? dout : hB;
        prop_kernel<<<pgrid, 256, 0, stream>>>(in, zbuf, rowptr, csr_src, csr_w, dinv, out, N);
    }
}

// Round 4
// 523.052 us; speedup vs baseline: 2.2760x; 1.1479x over previous
//
#include <hip/hip_runtime.h>

typedef __bf16 bf16x8 __attribute__((ext_vector_type(8)));
typedef float f32x4 __attribute__((ext_vector_type(4)));
typedef short short8 __attribute__((ext_vector_type(8)));

__device__ __forceinline__ unsigned short f2bf_u(float f) {
    unsigned u = __builtin_bit_cast(unsigned, f);
    u += 0x7FFFu + ((u >> 16) & 1u);   // RNE
    return (unsigned short)(u >> 16);
}
__device__ __forceinline__ float bf2f(unsigned short h) {
    unsigned u = ((unsigned)h) << 16;
    return __builtin_bit_cast(float, u);
}

#define GLOAD_LDS16(gsrc, ldst)                                                        \
    __builtin_amdgcn_global_load_lds((const __attribute__((address_space(1))) void*)(gsrc), \
                                     (__attribute__((address_space(3))) void*)(ldst), 16, 0, 0)

// ------------------------------------------------------------------
// Edge dtype detection: int64 input => odd 32-bit words all zero.
// ------------------------------------------------------------------
__global__ void detect_kernel(const unsigned int* __restrict__ edges, int* flag) {
    unsigned v = 0;
    for (int i = threadIdx.x * 2 + 1; i < 2048; i += 512) v |= edges[i];
    if (v) atomicOr(flag, 1);
}

__global__ void convert_count_kernel(const void* __restrict__ edges, const int* __restrict__ flag,
                                     int* __restrict__ src, int* __restrict__ dst,
                                     int* __restrict__ counts, int E) {
    int e = blockIdx.x * 256 + threadIdx.x;
    if (e >= E) return;
    int s, d;
    if (*flag) {  // int32
        const int* p = (const int*)edges;
        s = p[e];
        d = p[E + e];
    } else {      // int64
        const long long* p = (const long long*)edges;
        s = (int)p[e];
        d = (int)p[E + e];
    }
    src[e] = s;
    dst[e] = d;
    atomicAdd(&counts[d], 1);
}

__global__ void dinv_kernel(const int* __restrict__ counts, float* __restrict__ dinv, int n) {
    int i = blockIdx.x * 256 + threadIdx.x;
    if (i < n) dinv[i] = rsqrtf((float)counts[i] + 1.0f);
}

// ---------------- hierarchical exclusive scan ----------------
__global__ void blocksum_kernel(const int* __restrict__ counts, int* __restrict__ bs, int n) {
    __shared__ int sdata[256];
    int i = blockIdx.x * 256 + threadIdx.x;
    sdata[threadIdx.x] = (i < n) ? counts[i] : 0;
    __syncthreads();
    #pragma unroll
    for (int off = 128; off > 0; off >>= 1) {
        if (threadIdx.x < off) sdata[threadIdx.x] += sdata[threadIdx.x + off];
        __syncthreads();
    }
    if (threadIdx.x == 0) bs[blockIdx.x] = sdata[0];
}

__global__ void scanbs_kernel(const int* __restrict__ bs, int* __restrict__ bsoff, int nb) {
    __shared__ int sdata[256];
    int tid = threadIdx.x;
    int v = (tid < nb) ? bs[tid] : 0;
    sdata[tid] = v;
    __syncthreads();
    #pragma unroll
    for (int off = 1; off < 256; off <<= 1) {
        int t = (tid >= off) ? sdata[tid - off] : 0;
        __syncthreads();
        sdata[tid] += t;
        __syncthreads();
    }
    if (tid < nb) bsoff[tid] = sdata[tid] - v;
}

__global__ void scanblock_kernel(const int* __restrict__ counts, const int* __restrict__ bsoff,
                                 int* __restrict__ rowptr, int* __restrict__ cursor, int n) {
    __shared__ int sdata[256];
    int tid = threadIdx.x;
    int i = blockIdx.x * 256 + tid;
    int v = (i < n) ? counts[i] : 0;
    sdata[tid] = v;
    __syncthreads();
    #pragma unroll
    for (int off = 1; off < 256; off <<= 1) {
        int t = (tid >= off) ? sdata[tid - off] : 0;
        __syncthreads();
        sdata[tid] += t;
        __syncthreads();
    }
    int excl = bsoff[blockIdx.x] + sdata[tid] - v;
    if (i < n) { rowptr[i] = excl; cursor[i] = excl; }
    if (i == n - 1) rowptr[n] = excl + v;
}

__global__ void fill_kernel(const int* __restrict__ src, const int* __restrict__ dst,
                            const float* __restrict__ dinv, int* __restrict__ cursor,
                            int* __restrict__ csr_src, float* __restrict__ csr_w, int E) {
    int e = blockIdx.x * 256 + threadIdx.x;
    if (e >= E) return;
    int s = src[e], d = dst[e];
    int pos = atomicAdd(&cursor[d], 1);
    csr_src[pos] = s;
    csr_w[pos] = dinv[s] * dinv[d];
}

// ------------------------------------------------------------------
// Weight split: W -> Wh (bf16 RNE) + Wl (bf16 of residual)
// ------------------------------------------------------------------
__global__ void wsplit_kernel(const float* __restrict__ W, short* __restrict__ Wh,
                              short* __restrict__ Wl, int n) {
    int i = blockIdx.x * 256 + threadIdx.x;
    if (i >= n) return;
    float w = W[i];
    unsigned short h = f2bf_u(w);
    Wh[i] = (short)h;
    Wl[i] = (short)f2bf_u(w - bf2f(h));
}

// ------------------------------------------------------------------
// LDS-staged MFMA GEMM (m97 structure, single-buffered, 2 barriers/K-step).
// C[M,LDC-slice] = act(A[M,KDIM] @ (Bh+Bl)[BN-slice,KDIM]^T + bias)
// 256 threads = 4 waves (2x2), wave tile 64 x WN.
// LDS tiles XOR-swizzled in 16B units: unit(row,kg) at kg^(row&7)
// (A: reg-staged swizzled ds_write; B: linear global_load_lds dest with
//  inverse-swizzled global source — rule #21 both-sides discipline.)
// ------------------------------------------------------------------
template<int BN, int WN, int KDIM, int LDC, bool AF32, bool RELU, bool OUTBF16>
__global__ __launch_bounds__(256)
void gemm_lds(const void* __restrict__ Av, const short* __restrict__ Bh,
              const short* __restrict__ Bl, const float* __restrict__ bias,
              void* __restrict__ Cv, int M) {
    constexpr int BM = 128, BK = 64;
    constexpr int MI = 4;             // wave rows = 64
    constexpr int NI = WN / 16;
    constexpr int BPASS = BN / 32;
    __shared__ short sA[BM * BK];
    __shared__ short sBh[BN * BK];
    __shared__ short sBl[BN * BK];

    const int tid  = threadIdx.x;
    const int lane = tid & 63;
    const int wave = tid >> 6;
    const int wr = wave >> 1, wc = wave & 1;
    const int m0 = blockIdx.x * BM;
    const int n0 = blockIdx.y * BN;
    const int lr = lane & 15;
    const int lk = lane >> 4;
    const int tr = tid >> 3;          // staging row lane-group 0..31
    const int tk = tid & 7;           // staging 16B-unit 0..7

    f32x4 acc[MI][NI];
    #pragma unroll
    for (int mi = 0; mi < MI; ++mi)
        #pragma unroll
        for (int ni = 0; ni < NI; ++ni) acc[mi][ni] = {0.f, 0.f, 0.f, 0.f};

    #pragma unroll 1
    for (int k0 = 0; k0 < KDIM; k0 += BK) {
        // ---- stage A (128 x 64) ----
        if (AF32) {
            #pragma unroll
            for (int p = 0; p < 4; ++p) {
                int row = p * 32 + tr;
                int grow = m0 + row; if (grow > M - 1) grow = M - 1;
                const float* s = (const float*)Av + (size_t)grow * KDIM + k0 + tk * 8;
                float4 v0 = *reinterpret_cast<const float4*>(s);
                float4 v1 = *reinterpret_cast<const float4*>(s + 4);
                short8 sh;
                sh[0] = (short)f2bf_u(v0.x); sh[1] = (short)f2bf_u(v0.y);
                sh[2] = (short)f2bf_u(v0.z); sh[3] = (short)f2bf_u(v0.w);
                sh[4] = (short)f2bf_u(v1.x); sh[5] = (short)f2bf_u(v1.y);
                sh[6] = (short)f2bf_u(v1.z); sh[7] = (short)f2bf_u(v1.w);
                *reinterpret_cast<short8*>(&sA[row * 64 + ((tk ^ (row & 7)) << 3)]) = sh;
            }
        } else {
            #pragma unroll
            for (int p = 0; p < 4; ++p) {
                int row = p * 32 + tr;
                int grow = m0 + row; if (grow > M - 1) grow = M - 1;
                const short* s = (const short*)Av + (size_t)grow * KDIM + k0 + ((tk ^ (row & 7)) << 3);
                GLOAD_LDS16(s, &sA[p * 2048 + wave * 512]);
            }
        }
        // ---- stage Bh/Bl (BN x 64) via async DMA ----
        #pragma unroll
        for (int p = 0; p < BPASS; ++p) {
            int row = p * 32 + tr;
            size_t goff = (size_t)(n0 + row) * KDIM + k0 + ((tk ^ (row & 7)) << 3);
            GLOAD_LDS16(Bh + goff, &sBh[p * 2048 + wave * 512]);
            GLOAD_LDS16(Bl + goff, &sBl[p * 2048 + wave * 512]);
        }
        __syncthreads();   // drains vmcnt+lgkmcnt

        // ---- compute ----
        #pragma unroll
        for (int ks = 0; ks < 2; ++ks) {
            int kg = ks * 4 + lk;
            bf16x8 af[MI], bhf[NI], blf[NI];
            #pragma unroll
            for (int mi = 0; mi < MI; ++mi) {
                int row = wr * 64 + mi * 16 + lr;
                af[mi] = *reinterpret_cast<const bf16x8*>(&sA[row * 64 + ((kg ^ (row & 7)) << 3)]);
            }
            #pragma unroll
            for (int ni = 0; ni < NI; ++ni) {
                int row = wc * WN + ni * 16 + lr;
                int idx = row * 64 + ((kg ^ (row & 7)) << 3);
                bhf[ni] = *reinterpret_cast<const bf16x8*>(&sBh[idx]);
                blf[ni] = *reinterpret_cast<const bf16x8*>(&sBl[idx]);
            }
            #pragma unroll
            for (int mi = 0; mi < MI; ++mi)
                #pragma unroll
                for (int ni = 0; ni < NI; ++ni) {
                    acc[mi][ni] = __builtin_amdgcn_mfma_f32_16x16x32_bf16(af[mi], bhf[ni], acc[mi][ni], 0, 0, 0);
                    acc[mi][ni] = __builtin_amdgcn_mfma_f32_16x16x32_bf16(af[mi], blf[ni], acc[mi][ni], 0, 0, 0);
                }
        }
        __syncthreads();
    }

    // ---- epilogue ----
    #pragma unroll
    for (int ni = 0; ni < NI; ++ni) {
        int col = n0 + wc * WN + ni * 16 + lr;
        float bv = bias[col];
        #pragma unroll
        for (int mi = 0; mi < MI; ++mi) {
            #pragma unroll
            for (int r = 0; r < 4; ++r) {
                int row = m0 + wr * 64 + mi * 16 + lk * 4 + r;
                if (row < M) {
                    float v = acc[mi][ni][r] + bv;
                    if (RELU) v = fmaxf(v, 0.0f);
                    if (OUTBF16) ((short*)Cv)[(size_t)row * LDC + col] = (short)f2bf_u(v);
                    else         ((float*)Cv)[(size_t)row * LDC + col] = v;
                }
            }
        }
    }
}

// ------------------------------------------------------------------
// Propagation step: one wave per node, lane = channel; 8-edge batched gather.
// ------------------------------------------------------------------
__global__ __launch_bounds__(256)
void prop_kernel(const float* __restrict__ hin, const float* __restrict__ z,
                 const int* __restrict__ rowptr, const int* __restrict__ csr_src,
                 const float* __restrict__ csr_w, const float* __restrict__ dinv,
                 float* __restrict__ hout, int n) {
    int node = blockIdx.x * 4 + (threadIdx.x >> 6);
    int lane = threadIdx.x & 63;
    if (node >= n) return;
    float di = dinv[node];
    int base = node << 6;
    float acc = hin[base + lane] * (di * di);
    int e  = rowptr[node];
    int e1 = rowptr[node + 1];

    for (; e + 8 <= e1; e += 8) {
        int s[8]; float ww[8], v[8];
        #pragma unroll
        for (int j = 0; j < 8; ++j) { s[j] = csr_src[e + j]; ww[j] = csr_w[e + j]; }
        #pragma unroll
        for (int j = 0; j < 8; ++j) v[j] = hin[(s[j] << 6) + lane];
        #pragma unroll
        for (int j = 0; j < 8; ++j) acc = fmaf(v[j], ww[j], acc);
    }
    for (; e + 2 <= e1; e += 2) {
        int s0 = csr_src[e], s1 = csr_src[e + 1];
        float w0 = csr_w[e], w1 = csr_w[e + 1];
        float v0 = hin[(s0 << 6) + lane];
        float v1 = hin[(s1 << 6) + lane];
        acc = fmaf(v0, w0, acc);
        acc = fmaf(v1, w1, acc);
    }
    if (e < e1) {
        acc = fmaf(hin[(csr_src[e] << 6) + lane], csr_w[e], acc);
    }
    hout[base + lane] = 0.9f * acc + 0.1f * z[base + lane];
}

// ------------------------------------------------------------------
extern "C" void kernel_launch(void* const* d_in, const int* in_sizes, int n_in,
                              void* d_out, int out_size, void* d_ws, size_t ws_size,
                              hipStream_t stream) {
    const float* x  = (const float*)d_in[0];
    const void*  ei = d_in[1];
    const float* W1 = (const float*)d_in[2];
    const float* b1 = (const float*)d_in[3];
    const float* W2 = (const float*)d_in[4];
    const float* b2 = (const float*)d_in[5];
    float* dout = (float*)d_out;

    const int IN_C = 512, HID_C = 256, OUT_C = 64, Ksteps = 10;
    const int N = in_sizes[0] / IN_C;   // 50000
    const int E = in_sizes[1] / 2;      // 800000

    char* w = (char*)d_ws;
    auto alloc = [&](size_t bytes) { char* p = w; w += (bytes + 255) & ~(size_t)255; return p; };
    int*   flag    = (int*)  alloc(4);
    int*   src32   = (int*)  alloc((size_t)E * 4);
    int*   dst32   = (int*)  alloc((size_t)E * 4);
    int*   counts  = (int*)  alloc((size_t)N * 4);
    int*   rowptr  = (int*)  alloc((size_t)(N + 1) * 4);
    int*   cursor  = (int*)  alloc((size_t)N * 4);
    float* dinv    = (float*)alloc((size_t)N * 4);
    int*   csr_src = (int*)  alloc((size_t)E * 4);
    float* csr_w   = (float*)alloc((size_t)E * 4);
    short* W1h     = (short*)alloc((size_t)HID_C * IN_C * 2);
    short* W1l     = (short*)alloc((size_t)HID_C * IN_C * 2);
    short* W2h     = (short*)alloc((size_t)OUT_C * HID_C * 2);
    short* W2l     = (short*)alloc((size_t)OUT_C * HID_C * 2);
    short* Hbf     = (short*)alloc((size_t)N * HID_C * 2);
    float* zbuf    = (float*)alloc((size_t)N * OUT_C * 4);
    float* hB      = (float*)alloc((size_t)N * OUT_C * 4);
    int nblk = (N + 255) / 256;
    int*   bs      = (int*)  alloc((size_t)nblk * 4);
    int*   bsoff   = (int*)  alloc((size_t)nblk * 4);

    hipMemsetAsync(flag, 0, 4, stream);
    hipMemsetAsync(counts, 0, (size_t)N * 4, stream);

    int egrid = (E + 255) / 256;

    // weight splits (tiny)
    wsplit_kernel<<<(HID_C * IN_C + 255) / 256, 256, 0, stream>>>(W1, W1h, W1l, HID_C * IN_C);
    wsplit_kernel<<<(OUT_C * HID_C + 255) / 256, 256, 0, stream>>>(W2, W2h, W2l, OUT_C * HID_C);

    // graph preprocessing
    detect_kernel<<<1, 256, 0, stream>>>((const unsigned int*)ei, flag);
    convert_count_kernel<<<egrid, 256, 0, stream>>>(ei, flag, src32, dst32, counts, E);
    dinv_kernel<<<nblk, 256, 0, stream>>>(counts, dinv, N);
    blocksum_kernel<<<nblk, 256, 0, stream>>>(counts, bs, N);
    scanbs_kernel<<<1, 256, 0, stream>>>(bs, bsoff, nblk);
    scanblock_kernel<<<nblk, 256, 0, stream>>>(counts, bsoff, rowptr, cursor, N);
    fill_kernel<<<egrid, 256, 0, stream>>>(src32, dst32, dinv, cursor, csr_src, csr_w, E);

    // MLP on matrix cores (LDS-staged MFMA)
    int mgrid = (N + 127) / 128;
    dim3 g1(mgrid, 2);   // BN=128, N-total=256
    gemm_lds<128, 64, 512, 256, true, true, true>
        <<<g1, 256, 0, stream>>>(x, W1h, W1l, b1, Hbf, N);
    dim3 g2(mgrid, 1);   // BN=64 = full N
    gemm_lds<64, 32, 256, 64, false, false, false>
        <<<g2, 256, 0, stream>>>(Hbf, W2h, W2l, b2, zbuf, N);

    // K propagation steps. h^(0) = z lives in zbuf; steps ping-pong hB/dout,
    // ending in dout at s=9 (odd steps write dout).
    int pgrid = (N + 3) / 4;
    for (int s = 0; s < Ksteps; ++s) {
        const float* in  = (s == 0) ? zbuf : ((s & 1) ? hB : dout);
        float*       out = (s & 1) ? dout : hB;
        prop_kernel<<<pgrid, 256, 0, stream>>>(in, zbuf, rowptr, csr_src, csr_w, dinv, out, N);
    }
}